// Round 16
// baseline (30.340 us; speedup 1.0000x reference)
//
#include <hip/hip_runtime.h>

// PolyAttn collapse: a = s^4/|s^4| == 1.0 identically, so
//   out[b,n,:] = vsum[b,:] @ w_o,  vsum[b,:] = (sum_n x[b,n,:]) @ Wv.
// R16: compose ONLY measured-fast stages (R14/R11/R7 calibration):
//   kS = R7-kA verbatim (x in 5.4us, 1024 blk); narrow folds are ~1.5us
//   (R11-kFold measured); weight stages read rows coalesced, total traffic
//   ~78MB vs R13's ~180MB. 5 nodes, gaps ~0 (R7 anchor).
// Banned: grid barriers (~15us), spin-waits (~100us), deep strided j-loops
// (R12), per-block weight-slice redundancy blowup (R15).

#define B_ 4
#define N_ 2048
#define D_ 1024
#define H_ 1024
#define H3_ 3072

__device__ __forceinline__ void f4add(float4& a, const float4 b) {
    a.x += b.x; a.y += b.y; a.z += b.z; a.w += b.w;
}

// ws (floats): xpart[4][16][1024] 256KB | vspart[64][4][1024] 1MB |
//              opart[64][4][1024] 1MB  | orow[4][1024] 16KB

// ---- kS: 1024 blocks (b, ng 0..15, dq 0..15) — R7-kA verbatim --------------
__global__ __launch_bounds__(256) void kS(const float* __restrict__ x,
                                          float4* __restrict__ xpart4) {
    const int blk = blockIdx.x;
    const int t   = threadIdx.x;
    __shared__ float4 s4[16][16];
    const int b  = blk >> 8;
    const int ng = (blk >> 4) & 15;        // 16 groups of 128 rows
    const int dq = blk & 15;               // 16 slices of 64 floats
    const int d4 = t & 15;
    const int rr = t >> 4;                 // 16 row streams x 8 rows
    const float4* x4 = reinterpret_cast<const float4*>(x);
    size_t base = ((size_t)b * N_ + ng * 128 + rr * 8) * (D_ / 4) + dq * 16 + d4;
    float4 acc = make_float4(0.f, 0.f, 0.f, 0.f);
#pragma unroll 8
    for (int i = 0; i < 8; ++i)
        f4add(acc, x4[base + (size_t)i * (D_ / 4)]);
    s4[rr][d4] = acc;
    __syncthreads();
    if (t < 16) {
        float4 a = s4[0][t];
#pragma unroll 15
        for (int r = 1; r < 16; ++r) f4add(a, s4[r][t]);
        xpart4[((size_t)(b * 16 + ng)) * 256 + dq * 16 + t] = a;
    }
}

// ---- kV: 256 blocks (b, s 0..63): fold xpart 16-slice + 16 Wv rows ---------
__global__ __launch_bounds__(256) void kV(const float* __restrict__ xpart,
                                          const float* __restrict__ w_qkv,
                                          float4* __restrict__ vspart4) {
    const int blk = blockIdx.x;
    const int b = blk >> 6, s = blk & 63;
    const int t = threadIdx.x;
    __shared__ float s_x[256];             // [ng][c] 16x16

    // fold xpart[b][ng][s*16+c] over ng
    {
        const int ng = t >> 4, c = t & 15;
        s_x[t] = xpart[((size_t)(b * 16 + ng)) * 1024 + s * 16 + c];
    }
    __syncthreads();
    for (int off = 128; off >= 16; off >>= 1) {
        if (t < off) s_x[t] += s_x[t + off];
        __syncthreads();
    }
    // s_x[0..15] = cs[16]; apply 16 contiguous Wv rows (4KB coalesced each)
    const float4* wv4 = reinterpret_cast<const float4*>(w_qkv);
    float4 vp = make_float4(0.f, 0.f, 0.f, 0.f);
    size_t wbase = (size_t)(s * 16) * (H3_ / 4) + (2 * H_ / 4) + t;
#pragma unroll
    for (int j = 0; j < 16; ++j) {
        const float c = s_x[j];
        const float4 w = wv4[wbase + (size_t)j * (H3_ / 4)];
        vp.x += c * w.x; vp.y += c * w.y; vp.z += c * w.z; vp.w += c * w.w;
    }
    vspart4[(size_t)(s * 4 + b) * 256 + t] = vp;
}

// ---- kO: 64 blocks (hg 0..63): fold vspart h-slice + 16 Wo rows ------------
__global__ __launch_bounds__(256) void kO(const float4* __restrict__ vspart4,
                                          const float* __restrict__ w_o,
                                          float4* __restrict__ opart4) {
    const int hg = blockIdx.x;             // h rows hg*16 .. +16
    const int t  = threadIdx.x;
    __shared__ float4 s_tmp[64][4][4];     // [p][b][f4] = 16KB
    __shared__ float  s_vs[4][16];         // vsum slice [b][j]

    // gather vspart[p][b][hg*16..+16] (4 f4 = 64B contiguous per thread)
    {
        const int p = t >> 2, b = t & 3;
        const float4* src = vspart4 + (size_t)(p * 4 + b) * 256 + hg * 4;
#pragma unroll
        for (int k = 0; k < 4; ++k) s_tmp[p][b][k] = src[k];
    }
    __syncthreads();
    if (t < 64) {                          // t = b*16 + j: fold 64 p
        const int b = t >> 4, j = t & 15;
        float a = 0.f;
#pragma unroll
        for (int p = 0; p < 64; ++p)
            a += reinterpret_cast<const float*>(&s_tmp[p][b][0])[j];
        s_vs[b][j] = a;
    }
    __syncthreads();
    // apply 16 contiguous Wo rows (4KB coalesced each), 4 b accumulators
    const float4* wo4 = reinterpret_cast<const float4*>(w_o);
    float4 a0 = make_float4(0.f, 0.f, 0.f, 0.f), a1 = a0, a2 = a0, a3 = a0;
    size_t wbase = (size_t)(hg * 16) * (D_ / 4) + t;
#pragma unroll
    for (int j = 0; j < 16; ++j) {
        const float4 w = wo4[wbase + (size_t)j * (D_ / 4)];
        const float v0 = s_vs[0][j], v1 = s_vs[1][j];
        const float v2 = s_vs[2][j], v3 = s_vs[3][j];
        a0.x += v0 * w.x; a0.y += v0 * w.y; a0.z += v0 * w.z; a0.w += v0 * w.w;
        a1.x += v1 * w.x; a1.y += v1 * w.y; a1.z += v1 * w.z; a1.w += v1 * w.w;
        a2.x += v2 * w.x; a2.y += v2 * w.y; a2.z += v2 * w.z; a2.w += v2 * w.w;
        a3.x += v3 * w.x; a3.y += v3 * w.y; a3.z += v3 * w.z; a3.w += v3 * w.w;
    }
    opart4[(size_t)(hg * 4 + 0) * 256 + t] = a0;
    opart4[(size_t)(hg * 4 + 1) * 256 + t] = a1;
    opart4[(size_t)(hg * 4 + 2) * 256 + t] = a2;
    opart4[(size_t)(hg * 4 + 3) * 256 + t] = a3;
}

// ---- kF2: 4 blocks x 256 — R11-kFold verbatim on opart ---------------------
__global__ __launch_bounds__(256) void kF2(const float4* __restrict__ opart4,
                                           float4* __restrict__ orow4) {
    const int i = blockIdx.x * 256 + threadIdx.x;  // (b, d4)
    const int b = i >> 8, d4 = i & 255;
    const float4* p = opart4 + b * 256 + d4;
    float4 acc = make_float4(0.f, 0.f, 0.f, 0.f);
#pragma unroll 16
    for (int s = 0; s < 64; ++s)
        f4add(acc, p[(size_t)s * 1024]);
    orow4[i] = acc;
}

// ---- kB2: 2048 blocks x 256: out[b, 4 rows, :] = orow[b, :] ----------------
__global__ __launch_bounds__(256) void kB2(const float4* __restrict__ orow4,
                                           float4* __restrict__ out4) {
    const int blk = blockIdx.x;
    const int b   = blk >> 9;
    const int r0  = (blk & 511) * 4;
    const int t   = threadIdx.x;
    const float4 val = orow4[b * 256 + t];
    size_t base = ((size_t)b * N_ + r0) * (D_ / 4) + t;
#pragma unroll
    for (int i = 0; i < 4; ++i)
        out4[base + (size_t)i * (D_ / 4)] = val;
}

extern "C" void kernel_launch(void* const* d_in, const int* in_sizes, int n_in,
                              void* d_out, int out_size, void* d_ws, size_t ws_size,
                              hipStream_t stream) {
    const float* x     = (const float*)d_in[0];   // [B, N, D]
    const float* w_qkv = (const float*)d_in[1];   // [D, 3H]
    const float* w_o   = (const float*)d_in[2];   // [H, D]
    // d_in[3] = alpha — provably unused (a == 1 regardless of alpha).
    float* out = (float*)d_out;                   // [B, N, D] fp32

    float* xpart  = (float*)d_ws;                    // 16384 floats
    float* vspart = xpart + 16384;                   // 262144 floats
    float* opart  = vspart + 262144;                 // 262144 floats
    float* orow   = opart + 262144;                  // 4096 floats

    kS <<<1024, 256, 0, stream>>>(x, (float4*)xpart);
    kV <<<256,  256, 0, stream>>>(xpart, w_qkv, (float4*)vspart);
    kO <<<64,   256, 0, stream>>>((const float4*)vspart, w_o, (float4*)opart);
    kF2<<<4,    256, 0, stream>>>((const float4*)opart, (float4*)orow);
    kB2<<<2048, 256, 0, stream>>>((const float4*)orow, (float4*)out);
}